// Round 1
// baseline (171.165 us; speedup 1.0000x reference)
//
#include <hip/hip_runtime.h>

typedef _Float16 half8 __attribute__((ext_vector_type(8)));
typedef _Float16 half4v __attribute__((ext_vector_type(4)));
typedef float f32x4 __attribute__((ext_vector_type(4)));
typedef float float4v __attribute__((ext_vector_type(4)));

#define S_LEN 2048
#define D_DIM 64
#define QBLK 64
#define KVBLK 64
#define KSTR 72   // halves per row (pad 64->72 so row-starts hit different banks)
#define VSTR 72
#define PSTR 72

__global__ __launch_bounds__(256)
void fa_fwd_kernel(const float* __restrict__ Qg, const float* __restrict__ Kg,
                   const float* __restrict__ Vg, float* __restrict__ Og) {
  __shared__ _Float16 Klds[KVBLK * KSTR];
  __shared__ _Float16 Vtlds[D_DIM * VSTR];      // V transposed: [d][kv]
  __shared__ _Float16 Plds[4 * 16 * PSTR];      // per-wave P tile [16][64]

  const int tid  = (int)threadIdx.x;
  const int wid  = tid >> 6;
  const int lane = tid & 63;
  const int g    = lane >> 4;   // 0..3
  const int c    = lane & 15;   // 0..15

  const int qtile = (int)blockIdx.x;
  const int bh    = (int)blockIdx.y;
  const size_t base = (size_t)bh * (S_LEN * D_DIM);

  // ---- Q fragments: lane holds Q[qrow][kt*32 + 8g + j], j=0..7 (A-operand) ----
  const int qrow = qtile * QBLK + wid * 16 + c;
  half8 qf[2];
#pragma unroll
  for (int kt = 0; kt < 2; ++kt) {
    const float* qp = Qg + base + (size_t)qrow * D_DIM + kt * 32 + 8 * g;
    float4v a = *(const float4v*)qp;
    float4v b = *(const float4v*)(qp + 4);
    qf[kt][0] = (_Float16)a[0]; qf[kt][1] = (_Float16)a[1];
    qf[kt][2] = (_Float16)a[2]; qf[kt][3] = (_Float16)a[3];
    qf[kt][4] = (_Float16)b[0]; qf[kt][5] = (_Float16)b[1];
    qf[kt][6] = (_Float16)b[2]; qf[kt][7] = (_Float16)b[3];
  }

  const f32x4 zero4 = {0.f, 0.f, 0.f, 0.f};
  f32x4 o_acc[4];
  float m_run[4], l_run[4];
#pragma unroll
  for (int i = 0; i < 4; ++i) {
    o_acc[i] = zero4;
    m_run[i] = -1.0e30f;
    l_run[i] = 0.f;
  }

  const int srow = tid >> 4;         // 0..15
  const int scol = (tid & 15) * 4;   // 0..60

  for (int t = 0; t < S_LEN / KVBLK; ++t) {
    const int kv0 = t * KVBLK;
    __syncthreads();   // previous tile's LDS reads done before overwrite
    // ---- stage K (row-major f16) and V^T (d-major f16) ----
#pragma unroll
    for (int rr = 0; rr < 4; ++rr) {
      const int row = srow + rr * 16;
      const float* kp = Kg + base + (size_t)(kv0 + row) * D_DIM + scol;
      float4v kx = *(const float4v*)kp;
      half4v kh = { (_Float16)kx[0], (_Float16)kx[1], (_Float16)kx[2], (_Float16)kx[3] };
      *(half4v*)&Klds[row * KSTR + scol] = kh;
      const float* vp = Vg + base + (size_t)(kv0 + row) * D_DIM + scol;
      float4v vx = *(const float4v*)vp;
      Vtlds[(scol + 0) * VSTR + row] = (_Float16)vx[0];
      Vtlds[(scol + 1) * VSTR + row] = (_Float16)vx[1];
      Vtlds[(scol + 2) * VSTR + row] = (_Float16)vx[2];
      Vtlds[(scol + 3) * VSTR + row] = (_Float16)vx[3];
    }
    __syncthreads();

    // ---- S = Q K^T : per wave 16x64, 8 MFMA ----
    f32x4 s_acc[4];
#pragma unroll
    for (int ct = 0; ct < 4; ++ct) s_acc[ct] = zero4;
#pragma unroll
    for (int ct = 0; ct < 4; ++ct) {
#pragma unroll
      for (int kt = 0; kt < 2; ++kt) {
        // B-operand: lane holds K[ct*16 + c][kt*32 + 8g + j]
        half8 kb = *(half8*)&Klds[(ct * 16 + c) * KSTR + kt * 32 + 8 * g];
        s_acc[ct] = __builtin_amdgcn_mfma_f32_16x16x32_f16(qf[kt], kb, s_acc[ct], 0, 0, 0);
      }
    }

    // ---- online softmax (rows = 4g + r, cols = ct*16 + c) ----
#pragma unroll
    for (int r = 0; r < 4; ++r) {
      float smax = -1.0e30f;
#pragma unroll
      for (int ct = 0; ct < 4; ++ct) {
        s_acc[ct][r] *= 0.125f;                 // 1/sqrt(64)
        smax = fmaxf(smax, s_acc[ct][r]);
      }
#pragma unroll
      for (int off = 1; off < 16; off <<= 1)
        smax = fmaxf(smax, __shfl_xor(smax, off, 64));
      const float mnew  = fmaxf(m_run[r], smax);
      const float alpha = __expf(m_run[r] - mnew);
      m_run[r] = mnew;
      float psum = 0.f;
#pragma unroll
      for (int ct = 0; ct < 4; ++ct) {
        float p = __expf(s_acc[ct][r] - mnew);
        psum += p;
        Plds[(wid * 16 + g * 4 + r) * PSTR + ct * 16 + c] = (_Float16)p;
      }
#pragma unroll
      for (int off = 1; off < 16; off <<= 1)
        psum += __shfl_xor(psum, off, 64);
      l_run[r] = l_run[r] * alpha + psum;
#pragma unroll
      for (int dt = 0; dt < 4; ++dt) o_acc[dt][r] *= alpha;
    }

    // ---- O += P V : per wave 8 MFMA (DS ops in-order within wave; no barrier) ----
#pragma unroll
    for (int kc = 0; kc < 2; ++kc) {
      half8 pf = *(half8*)&Plds[(wid * 16 + c) * PSTR + kc * 32 + 8 * g];
#pragma unroll
      for (int dt = 0; dt < 4; ++dt) {
        half8 vf = *(half8*)&Vtlds[(dt * 16 + c) * VSTR + kc * 32 + 8 * g];
        o_acc[dt] = __builtin_amdgcn_mfma_f32_16x16x32_f16(pf, vf, o_acc[dt], 0, 0, 0);
      }
    }
  }

  // ---- epilogue: O /= l, write fp32 ----
  float inv[4];
#pragma unroll
  for (int r = 0; r < 4; ++r) inv[r] = 1.0f / l_run[r];
#pragma unroll
  for (int dt = 0; dt < 4; ++dt) {
#pragma unroll
    for (int r = 0; r < 4; ++r) {
      Og[base + (size_t)(qtile * QBLK + wid * 16 + g * 4 + r) * D_DIM + dt * 16 + c] =
          o_acc[dt][r] * inv[r];
    }
  }
}

extern "C" void kernel_launch(void* const* d_in, const int* in_sizes, int n_in,
                              void* d_out, int out_size, void* d_ws, size_t ws_size,
                              hipStream_t stream) {
  const float* Q = (const float*)d_in[0];
  const float* K = (const float*)d_in[1];
  const float* V = (const float*)d_in[2];
  float* O = (float*)d_out;
  dim3 grid(S_LEN / QBLK, 2 * 16);   // (q-tiles, b*h)
  dim3 block(256);
  hipLaunchKernelGGL(fa_fwd_kernel, grid, block, 0, stream, Q, K, V, O);
}

// Round 3
// 126.619 us; speedup vs baseline: 1.3518x; 1.3518x over previous
//
#include <hip/hip_runtime.h>
#include <stdint.h>

typedef _Float16 half8 __attribute__((ext_vector_type(8)));
typedef _Float16 half4 __attribute__((ext_vector_type(4)));
typedef float f32x4 __attribute__((ext_vector_type(4)));
typedef float float4v __attribute__((ext_vector_type(4)));

#define S_LEN 2048
#define D_DIM 64
#define QBLK 64
#define KVBLK 64
#define KSTR 72   // K row stride in halves (balanced for b128 reads)
#define PSTR 72

__global__ __launch_bounds__(256)
void fa_fwd_kernel(const float* __restrict__ Qg, const float* __restrict__ Kg,
                   const float* __restrict__ Vg, float* __restrict__ Og) {
  __shared__ _Float16 Klds[KVBLK * KSTR];
  __shared__ __attribute__((aligned(128))) _Float16 Vlds[KVBLK * D_DIM]; // [k>>2][d>>4][k&3][d&15]
  __shared__ _Float16 Plds[4 * 16 * PSTR];   // per-wave P tile [16][64]

  const int tid  = (int)threadIdx.x;
  const int wid  = tid >> 6;
  const int lane = tid & 63;
  const int g    = lane >> 4;   // 0..3
  const int c    = lane & 15;   // 0..15

  const int qtile = (int)blockIdx.x;
  const int bh    = (int)blockIdx.y;
  const size_t base = (size_t)bh * (S_LEN * D_DIM);

  // ---- Q fragments: lane holds Q[qrow][kt*32 + 8g + j], j=0..7 (A-operand) ----
  const int qrow = qtile * QBLK + wid * 16 + c;
  half8 qf[2];
#pragma unroll
  for (int kt = 0; kt < 2; ++kt) {
    const float* qp = Qg + base + (size_t)qrow * D_DIM + kt * 32 + 8 * g;
    float4v a = *(const float4v*)qp;
    float4v b = *(const float4v*)(qp + 4);
    half8 q;
    q[0] = (_Float16)a[0]; q[1] = (_Float16)a[1];
    q[2] = (_Float16)a[2]; q[3] = (_Float16)a[3];
    q[4] = (_Float16)b[0]; q[5] = (_Float16)b[1];
    q[6] = (_Float16)b[2]; q[7] = (_Float16)b[3];
    qf[kt] = q;
  }

  const f32x4 zero4 = {0.f, 0.f, 0.f, 0.f};
  f32x4 o_acc[4];
  float m_run[4], l_run[4];
#pragma unroll
  for (int i = 0; i < 4; ++i) {
    o_acc[i] = zero4;
    m_run[i] = -1.0e30f;
    l_run[i] = 0.f;
  }

  // K staging coords
  const int srow = tid >> 4;         // 0..15
  const int scol = (tid & 15) * 4;   // 0..60
  // V staging coords (subtiled layout [k>>2][d>>4][k&3][d&15])
  const int vgi = tid >> 4;          // k-chunk (k>>2): 0..15
  const int vlg = tid & 15;
  const int vk  = vgi * 4 + (vlg >> 2);   // k row 0..63
  const int vd0 = (vlg & 3) * 4;          // d offset within 16-chunk

  // per-lane tr-read base: 128B tile selected by (g + offset); column = c via low bits 8*c
  const uint32_t vtb = (uint32_t)(uintptr_t)(&Vlds[0]) + 1024u * (uint32_t)g + 8u * (uint32_t)c;

  for (int t = 0; t < S_LEN / KVBLK; ++t) {
    const int kv0 = t * KVBLK;
    __syncthreads();   // previous tile's LDS reads done before overwrite

    // ---- stage K row-major f16 (vectorized, bank-balanced) ----
#pragma unroll
    for (int rr = 0; rr < 4; ++rr) {
      const int row = srow + rr * 16;
      const float* kp = Kg + base + (size_t)(kv0 + row) * D_DIM + scol;
      float4v kx = *(const float4v*)kp;
      half4 kh = { (_Float16)kx[0], (_Float16)kx[1], (_Float16)kx[2], (_Float16)kx[3] };
      *(half4*)&Klds[row * KSTR + scol] = kh;
    }
    // ---- stage V subtiled [k>>2][d>>4][4][16] (vectorized half4 stores) ----
#pragma unroll
    for (int it = 0; it < 4; ++it) {
      const int d = it * 16 + vd0;
      const float* vp = Vg + base + (size_t)(kv0 + vk) * D_DIM + d;
      float4v vx = *(const float4v*)vp;
      half4 vh = { (_Float16)vx[0], (_Float16)vx[1], (_Float16)vx[2], (_Float16)vx[3] };
      *(half4*)&Vlds[vgi * 256 + it * 64 + (vlg >> 2) * 16 + (vlg & 3) * 4] = vh;
    }
    __syncthreads();

    // ---- S = Q K^T : per wave 16x64, 8 MFMA ----
    f32x4 s_acc[4];
#pragma unroll
    for (int ct = 0; ct < 4; ++ct) s_acc[ct] = zero4;
#pragma unroll
    for (int ct = 0; ct < 4; ++ct) {
#pragma unroll
      for (int kt = 0; kt < 2; ++kt) {
        half8 kb = *(half8*)&Klds[(ct * 16 + c) * KSTR + kt * 32 + 8 * g];
        s_acc[ct] = __builtin_amdgcn_mfma_f32_16x16x32_f16(qf[kt], kb, s_acc[ct], 0, 0, 0);
      }
    }

    // ---- online softmax (rows = 4g + r, cols = ct*16 + c) ----
#pragma unroll
    for (int r = 0; r < 4; ++r) {
      float smax = -1.0e30f;
#pragma unroll
      for (int ct = 0; ct < 4; ++ct) {
        s_acc[ct][r] *= 0.125f;                 // 1/sqrt(64)
        smax = fmaxf(smax, s_acc[ct][r]);
      }
#pragma unroll
      for (int off = 1; off < 16; off <<= 1)
        smax = fmaxf(smax, __shfl_xor(smax, off, 64));
      const float mnew  = fmaxf(m_run[r], smax);
      const float alpha = __expf(m_run[r] - mnew);
      m_run[r] = mnew;
      float psum = 0.f;
#pragma unroll
      for (int ct = 0; ct < 4; ++ct) {
        float p = __expf(s_acc[ct][r] - mnew);
        psum += p;
        Plds[(wid * 16 + g * 4 + r) * PSTR + ct * 16 + c] = (_Float16)p;
      }
#pragma unroll
      for (int off = 1; off < 16; off <<= 1)
        psum += __shfl_xor(psum, off, 64);
      l_run[r] = l_run[r] * alpha + psum;
#pragma unroll
      for (int dt = 0; dt < 4; ++dt) o_acc[dt][r] *= alpha;
    }

    // ---- O += P V : P via LDS (same-wave, DS in-order), V via HW transpose-read ----
    half8 pf0 = *(half8*)&Plds[(wid * 16 + c) * PSTR + 8 * g];
    half8 pf1 = *(half8*)&Plds[(wid * 16 + c) * PSTR + 32 + 8 * g];

    half4 vr[16];   // [kc*8 + h*4 + dt] : elems j -> V[kc*32+8g+4h+j][dt*16+c]
#define TRRD(i, offstr) \
    asm volatile("ds_read_b64_tr_b16 %0, %1 offset:" offstr : "=v"(vr[i]) : "v"(vtb))
    TRRD(0,  "0");    TRRD(1,  "128");  TRRD(2,  "256");  TRRD(3,  "384");
    TRRD(4,  "512");  TRRD(5,  "640");  TRRD(6,  "768");  TRRD(7,  "896");
    TRRD(8,  "4096"); TRRD(9,  "4224"); TRRD(10, "4352"); TRRD(11, "4480");
    TRRD(12, "4608"); TRRD(13, "4736"); TRRD(14, "4864"); TRRD(15, "4992");
#undef TRRD
    asm volatile("s_waitcnt lgkmcnt(0)" ::: "memory");
    __builtin_amdgcn_sched_barrier(0);

#pragma unroll
    for (int kc = 0; kc < 2; ++kc) {
      const half8 pf = kc ? pf1 : pf0;
#pragma unroll
      for (int dt = 0; dt < 4; ++dt) {
        half8 vf = __builtin_shufflevector(vr[kc * 8 + dt], vr[kc * 8 + 4 + dt],
                                           0, 1, 2, 3, 4, 5, 6, 7);
        o_acc[dt] = __builtin_amdgcn_mfma_f32_16x16x32_f16(pf, vf, o_acc[dt], 0, 0, 0);
      }
    }
  }

  // ---- epilogue: O /= l, write fp32 ----
  float inv[4];
#pragma unroll
  for (int r = 0; r < 4; ++r) inv[r] = 1.0f / l_run[r];
#pragma unroll
  for (int dt = 0; dt < 4; ++dt) {
#pragma unroll
    for (int r = 0; r < 4; ++r) {
      Og[base + (size_t)(qtile * QBLK + wid * 16 + g * 4 + r) * D_DIM + dt * 16 + c] =
          o_acc[dt][r] * inv[r];
    }
  }
}

extern "C" void kernel_launch(void* const* d_in, const int* in_sizes, int n_in,
                              void* d_out, int out_size, void* d_ws, size_t ws_size,
                              hipStream_t stream) {
  const float* Q = (const float*)d_in[0];
  const float* K = (const float*)d_in[1];
  const float* V = (const float*)d_in[2];
  float* O = (float*)d_out;
  dim3 grid(S_LEN / QBLK, 2 * 16);   // (q-tiles, b*h)
  dim3 block(256);
  hipLaunchKernelGGL(fa_fwd_kernel, grid, block, 0, stream, Q, K, V, O);
}

// Round 5
// 95.068 us; speedup vs baseline: 1.8005x; 1.3319x over previous
//
#include <hip/hip_runtime.h>
#include <stdint.h>

typedef _Float16 half8 __attribute__((ext_vector_type(8)));
typedef _Float16 half4 __attribute__((ext_vector_type(4)));
typedef __fp16 fp16x2 __attribute__((ext_vector_type(2)));
typedef float f32x4 __attribute__((ext_vector_type(4)));
typedef float float4v __attribute__((ext_vector_type(4)));

#define S_LEN 2048
#define D_DIM 64
#define QBLK 64
#define KVBLK 64
#define KSTR 72            // K row stride in halves (bank-balanced b128 reads)
#define QSCALE 0.18033688f // 0.125 * log2(e): softmax in base-2 domain

__global__ __launch_bounds__(256)
void fa_fwd_kernel(const float* __restrict__ Qg, const float* __restrict__ Kg,
                   const float* __restrict__ Vg, float* __restrict__ Og) {
  __shared__ _Float16 Klds[KVBLK * KSTR];
  // V in 128B subtiles for ds_read_b64_tr_b16. Subtile (vgi=k>>2, it=d>>4)
  // lives at 128B-tile index: it | 4*((vgi>>2)&1) | 8*(vgi&3) | 32*(vgi>>3)
  // so that tr-read instr (kc,h,dt) at lane-addr 1024g+8c + 128*(dt+4h+32kc)
  // delivers V[32kc+16h+4g+j][16dt+c]  (PV k-map: k = 32kc+16(j>>2)+4g+(j&3)).
  __shared__ __attribute__((aligned(128))) _Float16 Vlds[KVBLK * D_DIM];

  const int tid  = (int)threadIdx.x;
  const int wid  = tid >> 6;
  const int lane = tid & 63;
  const int g    = lane >> 4;   // 0..3
  const int c    = lane & 15;   // 0..15

  const int qtile = (int)blockIdx.x;
  const int bh    = (int)blockIdx.y;
  const size_t base = (size_t)bh * (S_LEN * D_DIM);

  // ---- Q fragments (B-operand of swapped QK^T), pre-scaled by QSCALE ----
  const int qrow = qtile * QBLK + wid * 16 + c;   // this lane's q-row
  half8 qf[2];
#pragma unroll
  for (int kt = 0; kt < 2; ++kt) {
    const float* qp = Qg + base + (size_t)qrow * D_DIM + kt * 32 + 8 * g;
    float4v a = *(const float4v*)qp;
    float4v b = *(const float4v*)(qp + 4);
    half8 q;
    q[0] = (_Float16)(a[0] * QSCALE); q[1] = (_Float16)(a[1] * QSCALE);
    q[2] = (_Float16)(a[2] * QSCALE); q[3] = (_Float16)(a[3] * QSCALE);
    q[4] = (_Float16)(b[0] * QSCALE); q[5] = (_Float16)(b[1] * QSCALE);
    q[6] = (_Float16)(b[2] * QSCALE); q[7] = (_Float16)(b[3] * QSCALE);
    qf[kt] = q;
  }

  const f32x4 zero4 = {0.f, 0.f, 0.f, 0.f};
  f32x4 o_acc[4];   // O^T[dv = dt*16 + 4g + r][q = qrow]
#pragma unroll
  for (int i = 0; i < 4; ++i) o_acc[i] = zero4;
  float m_run = -1.0e30f, l_run = 0.f;

  // K staging coords
  const int srow = tid >> 4;         // 0..15
  const int scol = (tid & 15) * 4;   // 0..60
  // V staging coords
  const int vgi = tid >> 4;          // k-chunk (k>>2): 0..15
  const int vlg = tid & 15;
  const int vk  = vgi * 4 + (vlg >> 2);   // k row 0..63
  const int vsub = 8 * (vgi & 3) + 4 * ((vgi >> 2) & 1) + 32 * (vgi >> 3);

  // per-lane tr-read base: tile via 1024g, column via 8c
  const uint32_t vtb = (uint32_t)(uintptr_t)(&Vlds[0]) + 1024u * (uint32_t)g + 8u * (uint32_t)c;

  for (int t = 0; t < S_LEN / KVBLK; ++t) {
    const int kv0 = t * KVBLK;
    __syncthreads();   // previous tile's LDS reads done before overwrite

    // ---- stage K row-major f16 (vectorized, bank-balanced) ----
#pragma unroll
    for (int rr = 0; rr < 4; ++rr) {
      const int row = srow + rr * 16;
      const float* kp = Kg + base + (size_t)(kv0 + row) * D_DIM + scol;
      float4v kx = *(const float4v*)kp;
      half4 kh = { (_Float16)kx[0], (_Float16)kx[1], (_Float16)kx[2], (_Float16)kx[3] };
      *(half4*)&Klds[row * KSTR + scol] = kh;
    }
    // ---- stage V into swizzled 128B subtiles ----
#pragma unroll
    for (int it = 0; it < 4; ++it) {
      const int d = it * 16 + (vlg & 3) * 4;
      const float* vp = Vg + base + (size_t)(kv0 + vk) * D_DIM + d;
      float4v vx = *(const float4v*)vp;
      half4 vh = { (_Float16)vx[0], (_Float16)vx[1], (_Float16)vx[2], (_Float16)vx[3] };
      *(half4*)&Vlds[(vsub + it) * 64 + (vlg >> 2) * 16 + (vlg & 3) * 4] = vh;
    }
    __syncthreads();

    // ---- S^T = K Q^T : lane holds S[k=16ct+4g+r][q=qrow] (pre-scaled) ----
    f32x4 s_acc[4];
#pragma unroll
    for (int ct = 0; ct < 4; ++ct) s_acc[ct] = zero4;
#pragma unroll
    for (int ct = 0; ct < 4; ++ct) {
#pragma unroll
      for (int kt = 0; kt < 2; ++kt) {
        half8 kb = *(half8*)&Klds[(ct * 16 + c) * KSTR + kt * 32 + 8 * g];
        s_acc[ct] = __builtin_amdgcn_mfma_f32_16x16x32_f16(kb, qf[kt], s_acc[ct], 0, 0, 0);
      }
    }

    // ---- online softmax, base-2, per-lane row q=qrow ----
    float pmax = -1.0e30f;
#pragma unroll
    for (int ct = 0; ct < 4; ++ct)
#pragma unroll
      for (int r = 0; r < 4; ++r) pmax = fmaxf(pmax, s_acc[ct][r]);
    pmax = fmaxf(pmax, __shfl_xor(pmax, 16, 64));
    pmax = fmaxf(pmax, __shfl_xor(pmax, 32, 64));
    const float mnew  = fmaxf(m_run, pmax);
    const float alpha = exp2f(m_run - mnew);
    m_run = mnew;

    float p[16];
    float psum = 0.f;
#pragma unroll
    for (int i = 0; i < 16; ++i) {
      p[i] = exp2f(s_acc[i >> 2][i & 3] - mnew);
      psum += p[i];
    }
    psum += __shfl_xor(psum, 16, 64);
    psum += __shfl_xor(psum, 32, 64);
    l_run = l_run * alpha + psum;
#pragma unroll
    for (int dt = 0; dt < 4; ++dt) {
      o_acc[dt][0] *= alpha; o_acc[dt][1] *= alpha;
      o_acc[dt][2] *= alpha; o_acc[dt][3] *= alpha;
    }

    // ---- pack P into B-fragments (lane-local, no LDS): pb[kc] = p[8kc..8kc+7] ----
    half8 pb[2];
#pragma unroll
    for (int kc = 0; kc < 2; ++kc) {
      fp16x2 x0 = __builtin_amdgcn_cvt_pkrtz(p[8 * kc + 0], p[8 * kc + 1]);
      fp16x2 x1 = __builtin_amdgcn_cvt_pkrtz(p[8 * kc + 2], p[8 * kc + 3]);
      fp16x2 x2 = __builtin_amdgcn_cvt_pkrtz(p[8 * kc + 4], p[8 * kc + 5]);
      fp16x2 x3 = __builtin_amdgcn_cvt_pkrtz(p[8 * kc + 6], p[8 * kc + 7]);
      half8 pk = { (_Float16)x0[0], (_Float16)x0[1], (_Float16)x1[0], (_Float16)x1[1],
                   (_Float16)x2[0], (_Float16)x2[1], (_Float16)x3[0], (_Float16)x3[1] };
      pb[kc] = pk;
    }

    // ---- V^T A-fragments via HW transpose-read ----
    half4 vr[16];   // [kc*8 + h*4 + dt] : elems j -> V[32kc+16h+4g+j][16dt+c]
#define TRRD(i, offstr) \
    asm volatile("ds_read_b64_tr_b16 %0, %1 offset:" offstr : "=v"(vr[i]) : "v"(vtb))
    TRRD(0,  "0");    TRRD(1,  "128");  TRRD(2,  "256");  TRRD(3,  "384");
    TRRD(4,  "512");  TRRD(5,  "640");  TRRD(6,  "768");  TRRD(7,  "896");
    TRRD(8,  "4096"); TRRD(9,  "4224"); TRRD(10, "4352"); TRRD(11, "4480");
    TRRD(12, "4608"); TRRD(13, "4736"); TRRD(14, "4864"); TRRD(15, "4992");
#undef TRRD
    asm volatile("s_waitcnt lgkmcnt(0)" ::: "memory");
    __builtin_amdgcn_sched_barrier(0);

    // ---- O^T += V^T P : A = V^T fragment, B = P fragment ----
#pragma unroll
    for (int kc = 0; kc < 2; ++kc) {
#pragma unroll
      for (int dt = 0; dt < 4; ++dt) {
        half8 vf = __builtin_shufflevector(vr[kc * 8 + dt], vr[kc * 8 + 4 + dt],
                                           0, 1, 2, 3, 4, 5, 6, 7);
        o_acc[dt] = __builtin_amdgcn_mfma_f32_16x16x32_f16(vf, pb[kc], o_acc[dt], 0, 0, 0);
      }
    }
  }

  // ---- epilogue: O = O^T^T / l, float4 stores (dv = dt*16 + 4g + r) ----
  const float invl = 1.0f / l_run;
#pragma unroll
  for (int dt = 0; dt < 4; ++dt) {
    float4v w = { o_acc[dt][0] * invl, o_acc[dt][1] * invl,
                  o_acc[dt][2] * invl, o_acc[dt][3] * invl };
    *(float4v*)&Og[base + (size_t)qrow * D_DIM + dt * 16 + g * 4] = w;
  }
}

extern "C" void kernel_launch(void* const* d_in, const int* in_sizes, int n_in,
                              void* d_out, int out_size, void* d_ws, size_t ws_size,
                              hipStream_t stream) {
  const float* Q = (const float*)d_in[0];
  const float* K = (const float*)d_in[1];
  const float* V = (const float*)d_in[2];
  float* O = (float*)d_out;
  dim3 grid(S_LEN / QBLK, 2 * 16);   // (q-tiles, b*h)
  dim3 block(256);
  hipLaunchKernelGGL(fa_fwd_kernel, grid, block, 0, stream, Q, K, V, O);
}